// Round 1
// baseline (9999.298 us; speedup 1.0000x reference)
//
#include <hip/hip_runtime.h>
#include <math.h>

#define NROWS 4096
#define CDIM 1024
#define ROOT_OUT 2002
#define T0_LO 2000
#define T0_HI 10000
#define T1_LO 10000
#define NUNITS 50257
#define T0_COLS 8000
#define T1_COLS 40257
#define BM 32

// ---------------- workspace layout (float units) ----------------
// H0 [4096][256] | H1 [4096][64] | S [3][4096] | P [3][4096] | idx0 | idx1 | cnt[2]
static constexpr size_t OFF_H0  = 0;
static constexpr size_t OFF_H1  = OFF_H0 + (size_t)NROWS * 256;
static constexpr size_t OFF_S   = OFF_H1 + (size_t)NROWS * 64;
static constexpr size_t OFF_P   = OFF_S + 3 * (size_t)NROWS;
static constexpr size_t OFF_I0  = OFF_P + 3 * (size_t)NROWS;
static constexpr size_t OFF_I1  = OFF_I0 + NROWS;
static constexpr size_t OFF_CNT = OFF_I1 + NROWS;

__global__ void zero_kernel(float* __restrict__ SP, int* __restrict__ cnt) {
  int i = blockIdx.x * 256 + threadIdx.x;
  if (i < 6 * NROWS) SP[i] = 0.f;
  if (i < 2) cnt[i] = 0;
}

__global__ void compact_kernel(const int* __restrict__ targets,
                               int* __restrict__ idx0, int* __restrict__ idx1,
                               int* __restrict__ cnt) {
  int n = blockIdx.x * 256 + threadIdx.x;
  if (n >= NROWS) return;
  int t = targets[n];
  if (t >= T0_LO && t < T0_HI) idx0[atomicAdd(&cnt[0], 1)] = n;
  else if (t >= T1_LO)         idx1[atomicAdd(&cnt[1], 1)] = n;
}

// H = logits[rows] @ W  for compacted rows only. 256 threads, BM=32 rows/block.
template<int DCOLS, int MCNT>
__global__ void hidden_kernel(const float* __restrict__ logits,
                              const float* __restrict__ W,   // [CDIM][DCOLS]
                              const int* __restrict__ idx,
                              const int* __restrict__ cnt, int which,
                              float* __restrict__ H) {
  const int tid = threadIdx.x;
  const int count = cnt[which];
  const int row0 = blockIdx.x * BM;
  if (row0 >= count) return;
  __shared__ float Alds[BM][64];
  __shared__ int row_lds[BM];
  if (tid < BM) row_lds[tid] = (row0 + tid < count) ? idx[row0 + tid] : -1;
  __syncthreads();
  float acc[MCNT];
#pragma unroll
  for (int i = 0; i < MCNT; i++) acc[i] = 0.f;
  const int col   = tid % DCOLS;
  const int mbase = (tid / DCOLS) * MCNT;
  const int sm  = tid >> 3;
  const int sko = (tid & 7) * 8;
  for (int kc = 0; kc < CDIM; kc += 64) {
    int row = row_lds[sm];
    float4 v0 = make_float4(0.f, 0.f, 0.f, 0.f), v1 = v0;
    if (row >= 0) {
      const float4* src = (const float4*)(logits + (size_t)row * CDIM + kc + sko);
      v0 = src[0]; v1 = src[1];
    }
    __syncthreads();
    *(float4*)&Alds[sm][sko]     = v0;
    *(float4*)&Alds[sm][sko + 4] = v1;
    __syncthreads();
#pragma unroll 2
    for (int k = 0; k < 64; k += 4) {
      float w0 = W[(size_t)(kc + k)     * DCOLS + col];
      float w1 = W[(size_t)(kc + k + 1) * DCOLS + col];
      float w2 = W[(size_t)(kc + k + 2) * DCOLS + col];
      float w3 = W[(size_t)(kc + k + 3) * DCOLS + col];
#pragma unroll
      for (int mm = 0; mm < MCNT; mm++) {
        float4 a = *(const float4*)&Alds[mbase + mm][k];
        acc[mm] = fmaf(a.x, w0, acc[mm]);
        acc[mm] = fmaf(a.y, w1, acc[mm]);
        acc[mm] = fmaf(a.z, w2, acc[mm]);
        acc[mm] = fmaf(a.w, w3, acc[mm]);
      }
    }
  }
#pragma unroll
  for (int mm = 0; mm < MCNT; mm++) {
    int row = row_lds[mbase + mm];
    if (row >= 0) H[(size_t)row * DCOLS + col] = acc[mm];
  }
}

// Fused GEMM + sum(exp) + picked-logit extraction.
// MODE: 0 = root (all rows, remapped targets), 1 = tail0, 2 = tail1 (compacted).
// Block: 256 threads, BM=32 rows, 512 cols per chunk (2 cols/thread).
template<int K, int KC, int MODE>
__global__ void ce_kernel(const float* __restrict__ A,   // [.][K], indexed by original row id
                          const float* __restrict__ W,   // [K][ncols]
                          int ncols, int chunks_per_block,
                          const int* __restrict__ idx,
                          const int* __restrict__ cnt,
                          const int* __restrict__ targets,
                          float* __restrict__ S,
                          float* __restrict__ P) {
  const int tid = threadIdx.x;
  const int count = (MODE == 0) ? NROWS : cnt[MODE - 1];
  const int row0 = blockIdx.x * BM;
  if (row0 >= count) return;
  __shared__ float Alds[BM][KC];
  __shared__ int row_lds[BM];
  __shared__ int tgt_lds[BM];
  __shared__ float sum_lds[BM];
  if (tid < BM) {
    int r = row0 + tid;
    int row = -1, tr = -1;
    if (r < count) {
      row = (MODE == 0) ? r : idx[r];
      int t = targets[row];
      if (MODE == 0)      tr = (t >= T0_LO && t < T0_HI) ? T0_LO : ((t >= T1_LO) ? (T0_LO + 1) : t);
      else if (MODE == 1) tr = t - T0_LO;
      else                tr = t - T1_LO;
    }
    row_lds[tid] = row;
    tgt_lds[tid] = tr;
    sum_lds[tid] = 0.f;
  }
  __syncthreads();

  const int sm  = tid >> 3;
  constexpr int PER = KC / 8;      // floats staged per thread
  const int sko = (tid & 7) * PER;
  const int cbase = blockIdx.y * chunks_per_block;

  for (int c = 0; c < chunks_per_block; c++) {
    const int jbase = (cbase + c) * 512;
    if (jbase >= ncols) break;     // uniform across block
    const int j0 = jbase + tid;
    const int j1 = jbase + 256 + tid;
    const bool v0c = j0 < ncols;
    const bool v1c = j1 < ncols;
    float acc0[BM], acc1[BM];
#pragma unroll
    for (int m = 0; m < BM; m++) { acc0[m] = 0.f; acc1[m] = 0.f; }

    for (int kc = 0; kc < K; kc += KC) {
      // stage A[BM][KC]
      int row = row_lds[sm];
      float4 v[PER / 4];
#pragma unroll
      for (int q = 0; q < PER / 4; q++) {
        v[q] = make_float4(0.f, 0.f, 0.f, 0.f);
        if (row >= 0)
          v[q] = ((const float4*)(A + (size_t)row * K + kc + sko))[q];
      }
      __syncthreads();
#pragma unroll
      for (int q = 0; q < PER / 4; q++)
        *(float4*)&Alds[sm][sko + q * 4] = v[q];
      __syncthreads();

#pragma unroll 2
      for (int k = 0; k < KC; k += 4) {
        float w00 = 0.f, w01 = 0.f, w02 = 0.f, w03 = 0.f;
        float w10 = 0.f, w11 = 0.f, w12 = 0.f, w13 = 0.f;
        if (v0c) {
          const float* wp = W + (size_t)(kc + k) * ncols + j0;
          w00 = wp[0]; w01 = wp[(size_t)ncols]; w02 = wp[2 * (size_t)ncols]; w03 = wp[3 * (size_t)ncols];
        }
        if (v1c) {
          const float* wp = W + (size_t)(kc + k) * ncols + j1;
          w10 = wp[0]; w11 = wp[(size_t)ncols]; w12 = wp[2 * (size_t)ncols]; w13 = wp[3 * (size_t)ncols];
        }
#pragma unroll
        for (int m = 0; m < BM; m++) {
          float4 a = *(const float4*)&Alds[m][k];
          acc0[m] = fmaf(a.x, w00, acc0[m]);
          acc0[m] = fmaf(a.y, w01, acc0[m]);
          acc0[m] = fmaf(a.z, w02, acc0[m]);
          acc0[m] = fmaf(a.w, w03, acc0[m]);
          acc1[m] = fmaf(a.x, w10, acc1[m]);
          acc1[m] = fmaf(a.y, w11, acc1[m]);
          acc1[m] = fmaf(a.z, w12, acc1[m]);
          acc1[m] = fmaf(a.w, w13, acc1[m]);
        }
      }
    }

    // per-row: exp, wave butterfly reduce, LDS accumulate; picked by compare
#pragma unroll
    for (int m = 0; m < BM; m++) {
      float e = 0.f;
      if (v0c) e += __expf(acc0[m]);
      if (v1c) e += __expf(acc1[m]);
      for (int off = 32; off > 0; off >>= 1) e += __shfl_down(e, off);
      if ((tid & 63) == 0) atomicAdd(&sum_lds[m], e);
      int tr = tgt_lds[m];
      if (v0c && j0 == tr) P[row_lds[m]] = acc0[m];
      if (v1c && j1 == tr) P[row_lds[m]] = acc1[m];
    }
  }
  __syncthreads();
  if (tid < BM) {
    int row = row_lds[tid];
    if (row >= 0) atomicAdd(&S[row], sum_lds[tid]);
  }
}

__global__ void loss_kernel(const int* __restrict__ targets,
                            const float* __restrict__ S,   // [3][NROWS]
                            const float* __restrict__ P,   // [3][NROWS]
                            float* __restrict__ out) {
  const int tid = threadIdx.x;
  float sr = 0.f, s0 = 0.f, s1 = 0.f, c0 = 0.f, c1 = 0.f;
  for (int n = tid; n < NROWS; n += 256) {
    int t = targets[n];
    sr += logf(S[n]) - P[n];
    if (t >= T0_LO && t < T0_HI) { s0 += logf(S[NROWS + n])     - P[NROWS + n];     c0 += 1.f; }
    else if (t >= T1_LO)         { s1 += logf(S[2 * NROWS + n]) - P[2 * NROWS + n]; c1 += 1.f; }
  }
  for (int off = 32; off > 0; off >>= 1) {
    sr += __shfl_down(sr, off);
    s0 += __shfl_down(s0, off);
    s1 += __shfl_down(s1, off);
    c0 += __shfl_down(c0, off);
    c1 += __shfl_down(c1, off);
  }
  __shared__ float red[4][5];
  int wv = tid >> 6;
  if ((tid & 63) == 0) { red[wv][0] = sr; red[wv][1] = s0; red[wv][2] = s1; red[wv][3] = c0; red[wv][4] = c1; }
  __syncthreads();
  if (tid == 0) {
    sr = red[0][0] + red[1][0] + red[2][0] + red[3][0];
    s0 = red[0][1] + red[1][1] + red[2][1] + red[3][1];
    s1 = red[0][2] + red[1][2] + red[2][2] + red[3][2];
    c0 = red[0][3] + red[1][3] + red[2][3] + red[3][3];
    c1 = red[0][4] + red[1][4] + red[2][4] + red[3][4];
    float root_loss = sr / (float)NROWS;
    float l0 = s0 / fmaxf(c0, 1.f);
    float l1 = s1 / fmaxf(c1, 1.f);
    out[0] = (root_loss + l0 + l1) / 3.f;
  }
}

extern "C" void kernel_launch(void* const* d_in, const int* in_sizes, int n_in,
                              void* d_out, int out_size, void* d_ws, size_t ws_size,
                              hipStream_t stream) {
  const float* logits  = (const float*)d_in[0];
  const int*   targets = (const int*)d_in[1];
  const float* head    = (const float*)d_in[2];
  const float* proj0   = (const float*)d_in[3];
  const float* scale0  = (const float*)d_in[4];
  const float* proj1   = (const float*)d_in[5];
  const float* scale1  = (const float*)d_in[6];
  float* out = (float*)d_out;
  float* ws  = (float*)d_ws;

  float* H0  = ws + OFF_H0;
  float* H1  = ws + OFF_H1;
  float* S   = ws + OFF_S;
  float* P   = ws + OFF_P;
  int*   idx0 = (int*)(ws + OFF_I0);
  int*   idx1 = (int*)(ws + OFF_I1);
  int*   cnt  = (int*)(ws + OFF_CNT);

  zero_kernel<<<96, 256, 0, stream>>>(S, cnt);
  compact_kernel<<<16, 256, 0, stream>>>(targets, idx0, idx1, cnt);
  hidden_kernel<256, 32><<<128, 256, 0, stream>>>(logits, proj0, idx0, cnt, 0, H0);
  hidden_kernel<64, 8><<<128, 256, 0, stream>>>(logits, proj1, idx1, cnt, 1, H1);
  // root: 2002 cols -> 4 chunks of 512 (grid.y=2 x cpb=2)
  ce_kernel<1024, 64, 0><<<dim3(128, 2), 256, 0, stream>>>(
      logits, head, ROOT_OUT, 2, nullptr, nullptr, targets, S, P);
  // tail0: 8000 cols -> 16 chunks (grid.y=4 x cpb=4)
  ce_kernel<256, 256, 1><<<dim3(128, 4), 256, 0, stream>>>(
      H0, scale0, T0_COLS, 4, idx0, cnt, targets, S + NROWS, P + NROWS);
  // tail1: 40257 cols -> 80 chunks (grid.y=8 x cpb=10)
  ce_kernel<64, 64, 2><<<dim3(128, 8), 256, 0, stream>>>(
      H1, scale1, T1_COLS, 10, idx1, cnt, targets, S + 2 * NROWS, P + 2 * NROWS);
  loss_kernel<<<1, 256, 0, stream>>>(targets, S, P, out);
}

// Round 3
// 419.136 us; speedup vs baseline: 23.8569x; 23.8569x over previous
//
#include <hip/hip_runtime.h>
#include <math.h>

#define NROWS 4096
#define CDIM 1024
#define T0_LO 2000
#define T0_HI 10000
#define T1_LO 10000
#define ROOT_COLS 2002
#define ROOT_PAD 2048
#define T0_COLS 8000
#define T0_PAD 8000
#define T1_COLS 40257
#define T1_PAD 40320
#define HB_STRIDE 320

using short8  = __attribute__((ext_vector_type(8))) short;
using ushort8 = __attribute__((ext_vector_type(8))) unsigned short;
using floatx4 = __attribute__((ext_vector_type(4))) float;

__device__ __forceinline__ unsigned short f2bf(float x) {
  union { float f; unsigned int u; } v; v.f = x;
  unsigned int r = v.u + 0x7fffu + ((v.u >> 16) & 1u);
  return (unsigned short)(r >> 16);
}
__device__ __forceinline__ floatx4 mfma16(short8 a, short8 b, floatx4 c) {
  return __builtin_amdgcn_mfma_f32_16x16x32_bf16(a, b, c, 0, 0, 0);
}

// ---------------- workspace layout (bytes) ----------------
static constexpr size_t B_HB  = 0;                          // ushort[4096*320]
static constexpr size_t B_WP  = B_HB + 4096ull * 320 * 2;   // ushort[320*1024]
static constexpr size_t B_WH  = B_WP + 320ull * 1024 * 2;   // ushort[2048*1024]
static constexpr size_t B_WS0 = B_WH + 2048ull * 1024 * 2;  // ushort[8000*256]
static constexpr size_t B_WS1 = B_WS0 + 8000ull * 256 * 2;  // ushort[40320*64]
static constexpr size_t B_S   = B_WS1 + 40320ull * 64 * 2;  // float[3*4096]
static constexpr size_t B_P   = B_S + 3ull * 4096 * 4;      // float[3*4096]
static constexpr size_t B_I0  = B_P + 3ull * 4096 * 4;
static constexpr size_t B_I1  = B_I0 + 4096ull * 4;
static constexpr size_t B_CNT = B_I1 + 4096ull * 4;

__global__ void zero_kernel(float* __restrict__ S, int* __restrict__ cnt) {
  int i = blockIdx.x * 256 + threadIdx.x;
  if (i < 3 * NROWS) S[i] = 0.f;
  if (i < 2) cnt[i] = 0;
}

__global__ void compact_kernel(const int* __restrict__ targets,
                               int* __restrict__ idx0, int* __restrict__ idx1,
                               int* __restrict__ cnt) {
  int n = blockIdx.x * 256 + threadIdx.x;
  if (n >= NROWS) return;
  int t = targets[n];
  if (t >= T0_LO && t < T0_HI) idx0[atomicAdd(&cnt[0], 1)] = n;
  else if (t >= T1_LO)         idx1[atomicAdd(&cnt[1], 1)] = n;
}

// W [K][N] f32 row-major -> Wt [Npad][K] bf16 (rows >= N zero-filled)
__global__ void transpose_cast_kernel(const float* __restrict__ W,
                                      unsigned short* __restrict__ Wt,
                                      int K, int N, int Npad) {
  __shared__ float tile[32][33];
  int n0 = blockIdx.x * 32, k0 = blockIdx.y * 32;
  int tx = threadIdx.x, ty = threadIdx.y;  // 32 x 8
  for (int i = 0; i < 32; i += 8) {
    int k = k0 + ty + i, n = n0 + tx;
    tile[ty + i][tx] = (k < K && n < N) ? W[(size_t)k * N + n] : 0.f;
  }
  __syncthreads();
  for (int i = 0; i < 32; i += 8) {
    int n = n0 + ty + i, k = k0 + tx;
    if (n < Npad && k < K) Wt[(size_t)n * K + k] = f2bf(tile[tx][ty + i]);
  }
}

// K=1024 GEMM over all 4096 rows, BM=32, chunked K (4 x 256), A-frags in regs.
// STORE: write Hb bf16 (hidden proj). !STORE: fused root CE (exp-sum + picked).
template<int CPS, bool STORE>
__global__ __launch_bounds__(256) void gemmA_kernel(
    const float* __restrict__ logits,
    const unsigned short* __restrict__ Wt,  // [Npad][1024] bf16, n-major
    int ncols,
    const int* __restrict__ targets,
    float* __restrict__ S, float* __restrict__ P,
    unsigned short* __restrict__ Hb) {
  __shared__ unsigned short A_lds[32 * 256];
  __shared__ int tgt_lds[32];
  const int tid = threadIdx.x;
  const int row0 = blockIdx.x * 32;
  const int cg0 = blockIdx.y * CPS;
  if (!STORE && tid < 32) {
    int t = targets[row0 + tid];
    tgt_lds[tid] = (t >= T0_LO && t < T0_HI) ? T0_LO : ((t >= T1_LO) ? T0_LO + 1 : t);
  }
  const int lane = tid & 63, w = tid >> 6;
  const int m = lane & 15, quad = lane >> 4;
  const int keym = m & 7;
  const floatx4 zf = {0.f, 0.f, 0.f, 0.f};
  floatx4 acc[CPS][2];
#pragma unroll
  for (int ci = 0; ci < CPS; ci++) { acc[ci][0] = zf; acc[ci][1] = zf; }

  for (int h = 0; h < 4; h++) {
    __syncthreads();
    // stage 32 rows x 256 k (bf16, XOR-swizzled 16B chunks).
    // 32*256/8 = 1024 chunks / 256 threads = 4 iterations.  (i<8 was the
    // round-2 crash: rl reached 63 -> OOB logits read + LDS overrun.)
#pragma unroll
    for (int i = 0; i < (32 * 256 / 8) / 256; i++) {
      int c = tid + 256 * i;
      int rl = c >> 5;       // 32 chunks per row
      int cq = c & 31;
      const float* src = logits + (size_t)(row0 + rl) * CDIM + h * 256 + cq * 8;
      float4 v0 = *(const float4*)src;
      float4 v1 = *(const float4*)(src + 4);
      ushort8 hh;
      hh[0] = f2bf(v0.x); hh[1] = f2bf(v0.y); hh[2] = f2bf(v0.z); hh[3] = f2bf(v0.w);
      hh[4] = f2bf(v1.x); hh[5] = f2bf(v1.y); hh[6] = f2bf(v1.z); hh[7] = f2bf(v1.w);
      *(ushort8*)&A_lds[rl * 256 + ((cq ^ (rl & 7)) << 3)] = hh;
    }
    __syncthreads();
    short8 areg[2][8];
#pragma unroll
    for (int t = 0; t < 2; t++)
#pragma unroll
      for (int ks = 0; ks < 8; ks++) {
        int ch = ((ks << 2) + quad) ^ keym;
        areg[t][ks] = *(const short8*)&A_lds[(t * 16 + m) * 256 + (ch << 3)];
      }
#pragma unroll
    for (int ci = 0; ci < CPS; ci++) {
      int n = (cg0 + ci) * 64 + w * 16 + m;
      const unsigned short* Bp = Wt + (size_t)n * 1024 + h * 256 + quad * 8;
      floatx4 a0 = acc[ci][0], a1 = acc[ci][1];
#pragma unroll
      for (int ks = 0; ks < 8; ks++) {
        short8 b = *(const short8*)(Bp + ks * 32);
        a0 = mfma16(areg[0][ks], b, a0);
        a1 = mfma16(areg[1][ks], b, a1);
      }
      acc[ci][0] = a0; acc[ci][1] = a1;
    }
  }

  if (STORE) {
#pragma unroll
    for (int ci = 0; ci < CPS; ci++) {
      int n = (cg0 + ci) * 64 + w * 16 + m;
#pragma unroll
      for (int t = 0; t < 2; t++)
#pragma unroll
        for (int r = 0; r < 4; r++) {
          int row = row0 + t * 16 + quad * 4 + r;
          Hb[(size_t)row * HB_STRIDE + n] = f2bf(acc[ci][t][r]);
        }
    }
  } else {
    float runsum[2][4] = {{0.f, 0.f, 0.f, 0.f}, {0.f, 0.f, 0.f, 0.f}};
    int tgtr[2][4];
#pragma unroll
    for (int t = 0; t < 2; t++)
#pragma unroll
      for (int r = 0; r < 4; r++) tgtr[t][r] = tgt_lds[t * 16 + quad * 4 + r];
#pragma unroll
    for (int ci = 0; ci < CPS; ci++) {
      int n = (cg0 + ci) * 64 + w * 16 + m;
      bool cv = n < ncols;
#pragma unroll
      for (int t = 0; t < 2; t++)
#pragma unroll
        for (int r = 0; r < 4; r++) {
          float lg = acc[ci][t][r];
          if (cv) runsum[t][r] += __expf(lg);
          if (n == tgtr[t][r]) P[row0 + t * 16 + quad * 4 + r] = lg;
        }
    }
#pragma unroll
    for (int t = 0; t < 2; t++)
#pragma unroll
      for (int r = 0; r < 4; r++) {
        float e = runsum[t][r];
        e += __shfl_xor(e, 1); e += __shfl_xor(e, 2);
        e += __shfl_xor(e, 4); e += __shfl_xor(e, 8);
        if (m == 0) atomicAdd(&S[row0 + t * 16 + quad * 4 + r], e);
      }
  }
}

// Tail CE: compacted rows, bf16 A from Hb, single staged K chunk, A-frags in regs.
template<int K, int TILES, int MODE>
__global__ __launch_bounds__(256) void tail_ce_kernel(
    const unsigned short* __restrict__ Hb, int acol0,
    const unsigned short* __restrict__ Wt,  // [Npad][K] bf16
    int ncols, int cps,
    const int* __restrict__ idx, const int* __restrict__ cnt,
    const int* __restrict__ targets,
    float* __restrict__ S, float* __restrict__ P) {
  constexpr int BM = TILES * 16;
  constexpr int CpR = K / 8;
  constexpr int KS = K / 32;
  __shared__ unsigned short A_lds[BM * K];
  __shared__ int row_lds[BM];
  __shared__ int tgt_lds[BM];
  const int tid = threadIdx.x;
  const int count = cnt[MODE - 1];
  const int row0 = blockIdx.x * BM;
  if (row0 >= count) return;
  if (tid < BM) {
    int r = row0 + tid;
    int row = -1, tr = -1;
    if (r < count) {
      row = idx[r];
      tr = targets[row] - (MODE == 1 ? T0_LO : T1_LO);
    }
    row_lds[tid] = row; tgt_lds[tid] = tr;
  }
  __syncthreads();
#pragma unroll
  for (int i = 0; i < BM * CpR / 256; i++) {
    int c = tid + 256 * i;
    int rl = c / CpR, cq = c % CpR;
    int row = row_lds[rl];
    ushort8 v = {0, 0, 0, 0, 0, 0, 0, 0};
    if (row >= 0) v = *(const ushort8*)(Hb + (size_t)row * HB_STRIDE + acol0 + cq * 8);
    *(ushort8*)&A_lds[rl * K + ((cq ^ (rl & 7)) << 3)] = v;
  }
  __syncthreads();
  const int lane = tid & 63, w = tid >> 6;
  const int m = lane & 15, quad = lane >> 4, keym = m & 7;
  const floatx4 zf = {0.f, 0.f, 0.f, 0.f};
  short8 areg[TILES][KS];
#pragma unroll
  for (int t = 0; t < TILES; t++)
#pragma unroll
    for (int ks = 0; ks < KS; ks++) {
      int ch = ((ks << 2) + quad) ^ keym;
      areg[t][ks] = *(const short8*)&A_lds[(t * 16 + m) * K + (ch << 3)];
    }
  int grow[TILES][4], tgtr[TILES][4];
  float runsum[TILES][4];
#pragma unroll
  for (int t = 0; t < TILES; t++)
#pragma unroll
    for (int r = 0; r < 4; r++) {
      int rl = t * 16 + quad * 4 + r;
      grow[t][r] = row_lds[rl]; tgtr[t][r] = tgt_lds[rl];
      runsum[t][r] = 0.f;
    }
  const int cg0 = blockIdx.y * cps;
  for (int cg = cg0; cg < cg0 + cps; cg++) {
    if (cg * 64 >= ncols) break;
    int n = cg * 64 + w * 16 + m;
    const unsigned short* Bp = Wt + (size_t)n * K + quad * 8;
    floatx4 acc[TILES];
#pragma unroll
    for (int t = 0; t < TILES; t++) acc[t] = zf;
#pragma unroll
    for (int ks = 0; ks < KS; ks++) {
      short8 b = *(const short8*)(Bp + ks * 32);
#pragma unroll
      for (int t = 0; t < TILES; t++) acc[t] = mfma16(areg[t][ks], b, acc[t]);
    }
    bool cv = n < ncols;
#pragma unroll
    for (int t = 0; t < TILES; t++)
#pragma unroll
      for (int r = 0; r < 4; r++) {
        float lg = acc[t][r];
        if (cv && grow[t][r] >= 0) runsum[t][r] += __expf(lg);
        if (n == tgtr[t][r]) P[grow[t][r]] = lg;
      }
  }
#pragma unroll
  for (int t = 0; t < TILES; t++)
#pragma unroll
    for (int r = 0; r < 4; r++) {
      float e = runsum[t][r];
      e += __shfl_xor(e, 1); e += __shfl_xor(e, 2);
      e += __shfl_xor(e, 4); e += __shfl_xor(e, 8);
      if (m == 0 && grow[t][r] >= 0) atomicAdd(&S[grow[t][r]], e);
    }
}

__global__ void loss_kernel(const int* __restrict__ targets,
                            const float* __restrict__ S,   // [3][NROWS]
                            const float* __restrict__ P,   // [3][NROWS]
                            float* __restrict__ out) {
  const int tid = threadIdx.x;
  float sr = 0.f, s0 = 0.f, s1 = 0.f, c0 = 0.f, c1 = 0.f;
  for (int n = tid; n < NROWS; n += 256) {
    int t = targets[n];
    sr += logf(S[n]) - P[n];
    if (t >= T0_LO && t < T0_HI) { s0 += logf(S[NROWS + n])     - P[NROWS + n];     c0 += 1.f; }
    else if (t >= T1_LO)         { s1 += logf(S[2 * NROWS + n]) - P[2 * NROWS + n]; c1 += 1.f; }
  }
  for (int off = 32; off > 0; off >>= 1) {
    sr += __shfl_down(sr, off);
    s0 += __shfl_down(s0, off);
    s1 += __shfl_down(s1, off);
    c0 += __shfl_down(c0, off);
    c1 += __shfl_down(c1, off);
  }
  __shared__ float red[4][5];
  int wv = tid >> 6;
  if ((tid & 63) == 0) { red[wv][0] = sr; red[wv][1] = s0; red[wv][2] = s1; red[wv][3] = c0; red[wv][4] = c1; }
  __syncthreads();
  if (tid == 0) {
    sr = red[0][0] + red[1][0] + red[2][0] + red[3][0];
    s0 = red[0][1] + red[1][1] + red[2][1] + red[3][1];
    s1 = red[0][2] + red[1][2] + red[2][2] + red[3][2];
    c0 = red[0][3] + red[1][3] + red[2][3] + red[3][3];
    c1 = red[0][4] + red[1][4] + red[2][4] + red[3][4];
    float root_loss = sr / (float)NROWS;
    float l0 = s0 / fmaxf(c0, 1.f);
    float l1 = s1 / fmaxf(c1, 1.f);
    out[0] = (root_loss + l0 + l1) / 3.f;
  }
}

extern "C" void kernel_launch(void* const* d_in, const int* in_sizes, int n_in,
                              void* d_out, int out_size, void* d_ws, size_t ws_size,
                              hipStream_t stream) {
  const float* logits  = (const float*)d_in[0];
  const int*   targets = (const int*)d_in[1];
  const float* head    = (const float*)d_in[2];
  const float* proj0   = (const float*)d_in[3];
  const float* scale0  = (const float*)d_in[4];
  const float* proj1   = (const float*)d_in[5];
  const float* scale1  = (const float*)d_in[6];
  float* out = (float*)d_out;
  char* ws = (char*)d_ws;

  unsigned short* Hb  = (unsigned short*)(ws + B_HB);
  unsigned short* Wp  = (unsigned short*)(ws + B_WP);
  unsigned short* Wh  = (unsigned short*)(ws + B_WH);
  unsigned short* Ws0 = (unsigned short*)(ws + B_WS0);
  unsigned short* Ws1 = (unsigned short*)(ws + B_WS1);
  float* S = (float*)(ws + B_S);
  float* P = (float*)(ws + B_P);
  int* idx0 = (int*)(ws + B_I0);
  int* idx1 = (int*)(ws + B_I1);
  int* cnt  = (int*)(ws + B_CNT);

  zero_kernel<<<48, 256, 0, stream>>>(S, cnt);
  compact_kernel<<<16, 256, 0, stream>>>(targets, idx0, idx1, cnt);
  dim3 tb(32, 8);
  transpose_cast_kernel<<<dim3(8, 32), tb, 0, stream>>>(proj0, Wp, 1024, 256, 256);
  transpose_cast_kernel<<<dim3(2, 32), tb, 0, stream>>>(proj1, Wp + 256 * 1024, 1024, 64, 64);
  transpose_cast_kernel<<<dim3(64, 32), tb, 0, stream>>>(head, Wh, 1024, ROOT_COLS, ROOT_PAD);
  transpose_cast_kernel<<<dim3(250, 8), tb, 0, stream>>>(scale0, Ws0, 256, T0_COLS, T0_PAD);
  transpose_cast_kernel<<<dim3(1260, 2), tb, 0, stream>>>(scale1, Ws1, 64, T1_COLS, T1_PAD);
  // hidden projections: Hb[4096][320] = bf16( logits @ [proj0 | proj1] )
  gemmA_kernel<5, true><<<dim3(128, 1), 256, 0, stream>>>(logits, Wp, 320, nullptr, nullptr, nullptr, Hb);
  // root CE: 2002 cols, 32 col-groups = 8 y-blocks x 4
  gemmA_kernel<4, false><<<dim3(128, 8), 256, 0, stream>>>(logits, Wh, ROOT_COLS, targets, S, P, nullptr);
  // tail0: K=256, BM=32, 125 cgs = 25 y-blocks x 5
  tail_ce_kernel<256, 2, 1><<<dim3(128, 25), 256, 0, stream>>>(
      Hb, 0, Ws0, T0_COLS, 5, idx0, cnt, targets, S + NROWS, P + NROWS);
  // tail1: K=64, BM=64, 630 cgs = 16 y-blocks x 40
  tail_ce_kernel<64, 4, 2><<<dim3(64, 16), 256, 0, stream>>>(
      Hb, 256, Ws1, T1_COLS, 40, idx1, cnt, targets, S + 2 * NROWS, P + 2 * NROWS);
  loss_kernel<<<1, 256, 0, stream>>>(targets, S, P, out);
}

// Round 4
// 313.945 us; speedup vs baseline: 31.8505x; 1.3351x over previous
//
#include <hip/hip_runtime.h>
#include <math.h>

#define NROWS 4096
#define CDIM 1024
#define T0_LO 2000
#define T0_HI 10000
#define T1_LO 10000
#define ROOT_COLS 2002
#define ROOT_PAD 2048
#define T0_COLS 8000
#define T1_COLS 40257
#define T1_PAD 40320
#define HB_STRIDE 320
#define LOG2E 1.44269504088896340736f
#define LN2 0.69314718055994530942f

using short8  = __attribute__((ext_vector_type(8))) short;
using ushort8 = __attribute__((ext_vector_type(8))) unsigned short;
using floatx4 = __attribute__((ext_vector_type(4))) float;

__device__ __forceinline__ unsigned short f2bf(float x) {
  union { float f; unsigned int u; } v; v.f = x;
  unsigned int r = v.u + 0x7fffu + ((v.u >> 16) & 1u);
  return (unsigned short)(r >> 16);
}
__device__ __forceinline__ float bf2f(unsigned short h) {
  union { unsigned int u; float f; } v; v.u = ((unsigned int)h) << 16;
  return v.f;
}
__device__ __forceinline__ floatx4 mfma16(short8 a, short8 b, floatx4 c) {
  return __builtin_amdgcn_mfma_f32_16x16x32_bf16(a, b, c, 0, 0, 0);
}

// ---------------- workspace layout (bytes) ----------------
static constexpr size_t B_HB  = 0;                          // ushort[4096*320]
static constexpr size_t B_WP  = B_HB + 4096ull * 320 * 2;   // ushort[320*1024]   (UNSCALED)
static constexpr size_t B_WH  = B_WP + 320ull * 1024 * 2;   // ushort[2048*1024]  (x log2e)
static constexpr size_t B_WS0 = B_WH + 2048ull * 1024 * 2;  // ushort[8000*256]   (x log2e)
static constexpr size_t B_WS1 = B_WS0 + 8000ull * 256 * 2;  // ushort[40320*64]   (x log2e)
static constexpr size_t B_S   = B_WS1 + 40320ull * 64 * 2;  // float[3*4096]
static constexpr size_t B_P   = B_S + 3ull * 4096 * 4;      // float[3*4096]
static constexpr size_t B_I0  = B_P + 3ull * 4096 * 4;
static constexpr size_t B_I1  = B_I0 + 4096ull * 4;
static constexpr size_t B_CNT = B_I1 + 4096ull * 4;

__global__ void zero_kernel(float* __restrict__ S, int* __restrict__ cnt) {
  int i = blockIdx.x * 256 + threadIdx.x;
  if (i < 3 * NROWS) S[i] = 0.f;
  if (i < 2) cnt[i] = 0;
}

__global__ void compact_kernel(const int* __restrict__ targets,
                               int* __restrict__ idx0, int* __restrict__ idx1,
                               int* __restrict__ cnt) {
  int n = blockIdx.x * 256 + threadIdx.x;
  if (n >= NROWS) return;
  int t = targets[n];
  if (t >= T0_LO && t < T0_HI) idx0[atomicAdd(&cnt[0], 1)] = n;
  else if (t >= T1_LO)         idx1[atomicAdd(&cnt[1], 1)] = n;
}

// W [K][N] f32 row-major -> Wt [Npad][K] bf16 = bf16(W^T * scale); pad rows zero.
__global__ void transpose_cast_kernel(const float* __restrict__ W,
                                      unsigned short* __restrict__ Wt,
                                      int K, int N, int Npad, float scale) {
  __shared__ float tile[32][33];
  int n0 = blockIdx.x * 32, k0 = blockIdx.y * 32;
  int tx = threadIdx.x, ty = threadIdx.y;  // 32 x 8
  for (int i = 0; i < 32; i += 8) {
    int k = k0 + ty + i, n = n0 + tx;
    tile[ty + i][tx] = (k < K && n < N) ? W[(size_t)k * N + n] * scale : 0.f;
  }
  __syncthreads();
  for (int i = 0; i < 32; i += 8) {
    int n = n0 + ty + i, k = k0 + tx;
    if (n < Npad && k < K) Wt[(size_t)n * K + k] = f2bf(tile[tx][ty + i]);
  }
}

// K=1024 GEMM over all 4096 rows, BM=64 (4 row-tiles), K-chunk 128, A-frags in regs.
// STORE: write Hb bf16 (hidden proj, unscaled W). !STORE: root CE exp2-sum.
template<int CPS, bool STORE>
__global__ __launch_bounds__(256) void gemmA_kernel(
    const float* __restrict__ logits,
    const unsigned short* __restrict__ Wt,  // [Npad][1024] bf16, n-major
    float* __restrict__ S,
    unsigned short* __restrict__ Hb) {
  __shared__ unsigned short A_lds[64 * 128];  // 16 KB
  __shared__ float sum_lds[64];
  const int tid = threadIdx.x;
  const int row0 = blockIdx.x * 64;
  const int cg0 = blockIdx.y * CPS;
  if (!STORE && tid < 64) sum_lds[tid] = 0.f;
  const int lane = tid & 63, w = tid >> 6;
  const int m = lane & 15, quad = lane >> 4;
  const int keym = m & 7;
  const floatx4 zf = {0.f, 0.f, 0.f, 0.f};
  floatx4 acc[CPS][4];
#pragma unroll
  for (int ci = 0; ci < CPS; ci++)
#pragma unroll
    for (int t = 0; t < 4; t++) acc[ci][t] = zf;

  for (int h = 0; h < 8; h++) {
    __syncthreads();
    // stage 64 rows x 128 k bf16: 64*128/8 = 1024 chunks / 256 thr = 4 iters
#pragma unroll
    for (int i = 0; i < 4; i++) {
      int c = tid + 256 * i;
      int rl = c >> 4;       // 16 chunks per row
      int cq = c & 15;
      const float* src = logits + (size_t)(row0 + rl) * CDIM + h * 128 + cq * 8;
      float4 v0 = *(const float4*)src;
      float4 v1 = *(const float4*)(src + 4);
      ushort8 hh;
      hh[0] = f2bf(v0.x); hh[1] = f2bf(v0.y); hh[2] = f2bf(v0.z); hh[3] = f2bf(v0.w);
      hh[4] = f2bf(v1.x); hh[5] = f2bf(v1.y); hh[6] = f2bf(v1.z); hh[7] = f2bf(v1.w);
      *(ushort8*)&A_lds[rl * 128 + ((cq ^ (rl & 7)) << 3)] = hh;
    }
    __syncthreads();
    short8 areg[4][4];
#pragma unroll
    for (int t = 0; t < 4; t++)
#pragma unroll
      for (int ks = 0; ks < 4; ks++) {
        int ch = ((ks << 2) + quad) ^ keym;
        areg[t][ks] = *(const short8*)&A_lds[(t * 16 + m) * 128 + (ch << 3)];
      }
#pragma unroll
    for (int ci = 0; ci < CPS; ci++) {
      int n = (cg0 + ci) * 64 + w * 16 + m;
      const unsigned short* Bp = Wt + (size_t)n * 1024 + h * 128 + quad * 8;
#pragma unroll
      for (int ks = 0; ks < 4; ks++) {
        short8 b = *(const short8*)(Bp + ks * 32);
#pragma unroll
        for (int t = 0; t < 4; t++) acc[ci][t] = mfma16(areg[t][ks], b, acc[ci][t]);
      }
    }
  }

  if (STORE) {
#pragma unroll
    for (int ci = 0; ci < CPS; ci++) {
      int n = (cg0 + ci) * 64 + w * 16 + m;
#pragma unroll
      for (int t = 0; t < 4; t++)
#pragma unroll
        for (int r = 0; r < 4; r++) {
          int row = row0 + t * 16 + quad * 4 + r;
          Hb[(size_t)row * HB_STRIDE + n] = f2bf(acc[ci][t][r]);
        }
    }
  } else {
#pragma unroll
    for (int t = 0; t < 4; t++)
#pragma unroll
      for (int r = 0; r < 4; r++) {
        float e = 0.f;
#pragma unroll
        for (int ci = 0; ci < CPS; ci++) e += __builtin_amdgcn_exp2f(acc[ci][t][r]);
        e += __shfl_xor(e, 1); e += __shfl_xor(e, 2);
        e += __shfl_xor(e, 4); e += __shfl_xor(e, 8);
        if (m == 0) atomicAdd(&sum_lds[t * 16 + quad * 4 + r], e);
      }
    __syncthreads();
    if (tid < 64) atomicAdd(&S[row0 + tid], sum_lds[tid]);
  }
}

// Tail CE: compacted rows, bf16 A from Hb, exp2-sum only, B prefetch.
template<int K, int TILES, int MODE>
__global__ __launch_bounds__(256) void tail_ce_kernel(
    const unsigned short* __restrict__ Hb, int acol0,
    const unsigned short* __restrict__ Wt,  // [Npad][K] bf16, x log2e
    int cps,
    const int* __restrict__ idx, const int* __restrict__ cnt,
    float* __restrict__ S) {
  constexpr int BM = TILES * 16;
  constexpr int CpR = K / 8;
  constexpr int KS = K / 32;
  __shared__ unsigned short A_lds[BM * K];
  __shared__ int row_lds[BM];
  __shared__ float sum_lds[BM];
  const int tid = threadIdx.x;
  const int count = cnt[MODE - 1];
  const int row0 = blockIdx.x * BM;
  if (row0 >= count) return;
  if (tid < BM) {
    int r = row0 + tid;
    row_lds[tid] = (r < count) ? idx[r] : -1;
    sum_lds[tid] = 0.f;
  }
  __syncthreads();
#pragma unroll
  for (int i = 0; i < BM * CpR / 256; i++) {
    int c = tid + 256 * i;
    int rl = c / CpR, cq = c % CpR;
    int row = row_lds[rl];
    ushort8 v = {0, 0, 0, 0, 0, 0, 0, 0};
    if (row >= 0) v = *(const ushort8*)(Hb + (size_t)row * HB_STRIDE + acol0 + cq * 8);
    *(ushort8*)&A_lds[rl * K + ((cq ^ (rl & 7)) << 3)] = v;
  }
  __syncthreads();
  const int lane = tid & 63, w = tid >> 6;
  const int m = lane & 15, quad = lane >> 4, keym = m & 7;
  const floatx4 zf = {0.f, 0.f, 0.f, 0.f};
  short8 areg[TILES][KS];
#pragma unroll
  for (int t = 0; t < TILES; t++)
#pragma unroll
    for (int ks = 0; ks < KS; ks++) {
      int ch = ((ks << 2) + quad) ^ keym;
      areg[t][ks] = *(const short8*)&A_lds[(t * 16 + m) * K + (ch << 3)];
    }
  float runsum[TILES][4];
#pragma unroll
  for (int t = 0; t < TILES; t++)
#pragma unroll
    for (int r = 0; r < 4; r++) runsum[t][r] = 0.f;

  const int cg0 = blockIdx.y * cps;
  const unsigned short* Bp = Wt + (size_t)(cg0 * 64 + w * 16 + m) * K + quad * 8;
  short8 bcur[KS];
#pragma unroll
  for (int ks = 0; ks < KS; ks++) bcur[ks] = *(const short8*)(Bp + ks * 32);
  for (int c = 0; c < cps; c++) {
    short8 bnx[KS];
    if (c + 1 < cps) {
      const unsigned short* Bn = Bp + (size_t)(c + 1) * 64 * K;
#pragma unroll
      for (int ks = 0; ks < KS; ks++) bnx[ks] = *(const short8*)(Bn + ks * 32);
    }
    floatx4 acc[TILES];
#pragma unroll
    for (int t = 0; t < TILES; t++) acc[t] = zf;
#pragma unroll
    for (int ks = 0; ks < KS; ks++)
#pragma unroll
      for (int t = 0; t < TILES; t++) acc[t] = mfma16(areg[t][ks], bcur[ks], acc[t]);
#pragma unroll
    for (int t = 0; t < TILES; t++)
#pragma unroll
      for (int r = 0; r < 4; r++) runsum[t][r] += __builtin_amdgcn_exp2f(acc[t][r]);
#pragma unroll
    for (int ks = 0; ks < KS; ks++) bcur[ks] = bnx[ks];
  }
#pragma unroll
  for (int t = 0; t < TILES; t++)
#pragma unroll
    for (int r = 0; r < 4; r++) {
      float e = runsum[t][r];
      e += __shfl_xor(e, 1); e += __shfl_xor(e, 2);
      e += __shfl_xor(e, 4); e += __shfl_xor(e, 8);
      if (m == 0) atomicAdd(&sum_lds[t * 16 + quad * 4 + r], e);
    }
  __syncthreads();
  if (tid < BM) {
    int row = row_lds[tid];
    if (row >= 0) atomicAdd(&S[row], sum_lds[tid]);
  }
}

// Picked logits: wave per row. root always; one tail if routed. x ln2 (weights
// carry log2e).
__global__ __launch_bounds__(256) void picked_kernel(
    const float* __restrict__ logits, const int* __restrict__ targets,
    const unsigned short* __restrict__ Wh,
    const unsigned short* __restrict__ Ws0,
    const unsigned short* __restrict__ Ws1,
    const unsigned short* __restrict__ Hb,
    float* __restrict__ P) {
  const int tid = threadIdx.x, lane = tid & 63;
  const int row = blockIdx.x * 4 + (tid >> 6);
  const int t = targets[row];
  const int tr = (t >= T0_LO && t < T0_HI) ? T0_LO : ((t >= T1_LO) ? T0_LO + 1 : t);
  const float* a = logits + (size_t)row * CDIM + lane * 16;
  const unsigned short* wr = Wh + (size_t)tr * CDIM + lane * 16;
  float acc = 0.f;
#pragma unroll
  for (int q = 0; q < 2; q++) {
    ushort8 wv = *(const ushort8*)(wr + q * 8);
    float4 a0 = ((const float4*)a)[q * 2];
    float4 a1 = ((const float4*)a)[q * 2 + 1];
    acc += a0.x * bf2f(wv[0]) + a0.y * bf2f(wv[1]) + a0.z * bf2f(wv[2]) + a0.w * bf2f(wv[3]);
    acc += a1.x * bf2f(wv[4]) + a1.y * bf2f(wv[5]) + a1.z * bf2f(wv[6]) + a1.w * bf2f(wv[7]);
  }
#pragma unroll
  for (int off = 1; off < 64; off <<= 1) acc += __shfl_xor(acc, off);
  if (lane == 0) P[row] = acc * LN2;
  if (t >= T0_LO) {
    float acc2 = 0.f;
    if (t < T0_HI) {
      const unsigned short* h = Hb + (size_t)row * HB_STRIDE + lane * 4;
      const unsigned short* w2 = Ws0 + (size_t)(t - T0_LO) * 256 + lane * 4;
#pragma unroll
      for (int j = 0; j < 4; j++) acc2 += bf2f(h[j]) * bf2f(w2[j]);
    } else {
      acc2 = bf2f(Hb[(size_t)row * HB_STRIDE + 256 + lane]) *
             bf2f(Ws1[(size_t)(t - T1_LO) * 64 + lane]);
    }
#pragma unroll
    for (int off = 1; off < 64; off <<= 1) acc2 += __shfl_xor(acc2, off);
    if (lane == 0) P[(t < T0_HI ? NROWS : 2 * NROWS) + row] = acc2 * LN2;
  }
}

__global__ void loss_kernel(const int* __restrict__ targets,
                            const float* __restrict__ S,   // [3][NROWS]
                            const float* __restrict__ P,   // [3][NROWS]
                            float* __restrict__ out) {
  const int tid = threadIdx.x;
  float sr = 0.f, s0 = 0.f, s1 = 0.f, c0 = 0.f, c1 = 0.f;
  for (int n = tid; n < NROWS; n += 256) {
    int t = targets[n];
    sr += logf(S[n] - 46.f) - P[n];  // 46 pad cols contribute exp2(0)=1 each
    if (t >= T0_LO && t < T0_HI) { s0 += logf(S[NROWS + n]) - P[NROWS + n]; c0 += 1.f; }
    else if (t >= T1_LO)         { s1 += logf(S[2 * NROWS + n] - 63.f) - P[2 * NROWS + n]; c1 += 1.f; }
  }
  for (int off = 32; off > 0; off >>= 1) {
    sr += __shfl_down(sr, off);
    s0 += __shfl_down(s0, off);
    s1 += __shfl_down(s1, off);
    c0 += __shfl_down(c0, off);
    c1 += __shfl_down(c1, off);
  }
  __shared__ float red[4][5];
  int wv = tid >> 6;
  if ((tid & 63) == 0) { red[wv][0] = sr; red[wv][1] = s0; red[wv][2] = s1; red[wv][3] = c0; red[wv][4] = c1; }
  __syncthreads();
  if (tid == 0) {
    sr = red[0][0] + red[1][0] + red[2][0] + red[3][0];
    s0 = red[0][1] + red[1][1] + red[2][1] + red[3][1];
    s1 = red[0][2] + red[1][2] + red[2][2] + red[3][2];
    c0 = red[0][3] + red[1][3] + red[2][3] + red[3][3];
    c1 = red[0][4] + red[1][4] + red[2][4] + red[3][4];
    float root_loss = sr / (float)NROWS;
    float l0 = s0 / fmaxf(c0, 1.f);
    float l1 = s1 / fmaxf(c1, 1.f);
    out[0] = (root_loss + l0 + l1) / 3.f;
  }
}

extern "C" void kernel_launch(void* const* d_in, const int* in_sizes, int n_in,
                              void* d_out, int out_size, void* d_ws, size_t ws_size,
                              hipStream_t stream) {
  const float* logits  = (const float*)d_in[0];
  const int*   targets = (const int*)d_in[1];
  const float* head    = (const float*)d_in[2];
  const float* proj0   = (const float*)d_in[3];
  const float* scale0  = (const float*)d_in[4];
  const float* proj1   = (const float*)d_in[5];
  const float* scale1  = (const float*)d_in[6];
  float* out = (float*)d_out;
  char* ws = (char*)d_ws;

  unsigned short* Hb  = (unsigned short*)(ws + B_HB);
  unsigned short* Wp  = (unsigned short*)(ws + B_WP);
  unsigned short* Wh  = (unsigned short*)(ws + B_WH);
  unsigned short* Ws0 = (unsigned short*)(ws + B_WS0);
  unsigned short* Ws1 = (unsigned short*)(ws + B_WS1);
  float* S = (float*)(ws + B_S);
  float* P = (float*)(ws + B_P);
  int* idx0 = (int*)(ws + B_I0);
  int* idx1 = (int*)(ws + B_I1);
  int* cnt  = (int*)(ws + B_CNT);

  zero_kernel<<<48, 256, 0, stream>>>(S, cnt);
  compact_kernel<<<16, 256, 0, stream>>>(targets, idx0, idx1, cnt);
  dim3 tb(32, 8);
  transpose_cast_kernel<<<dim3(8, 32), tb, 0, stream>>>(proj0, Wp, 1024, 256, 256, 1.f);
  transpose_cast_kernel<<<dim3(2, 32), tb, 0, stream>>>(proj1, Wp + 256 * 1024, 1024, 64, 64, 1.f);
  transpose_cast_kernel<<<dim3(64, 32), tb, 0, stream>>>(head, Wh, 1024, ROOT_COLS, ROOT_PAD, LOG2E);
  transpose_cast_kernel<<<dim3(250, 8), tb, 0, stream>>>(scale0, Ws0, 256, T0_COLS, T0_COLS, LOG2E);
  transpose_cast_kernel<<<dim3(1260, 2), tb, 0, stream>>>(scale1, Ws1, 64, T1_COLS, T1_PAD, LOG2E);
  // hidden projections: Hb[4096][320] = bf16( logits @ [proj0 | proj1] )
  gemmA_kernel<1, true><<<dim3(64, 5), 256, 0, stream>>>(logits, Wp, nullptr, Hb);
  // root CE: 2048 pad cols = 32 cgs = 16 y-blocks x CPS 2
  gemmA_kernel<2, false><<<dim3(64, 16), 256, 0, stream>>>(logits, Wh, S, nullptr);
  // tail0: K=256, BM=32, 125 cgs = 25 y x 5
  tail_ce_kernel<256, 2, 1><<<dim3(128, 25), 256, 0, stream>>>(
      Hb, 0, Ws0, 5, idx0, cnt, S + NROWS);
  // tail1: K=64, BM=64, 630 cgs = 63 y x 10
  tail_ce_kernel<64, 4, 2><<<dim3(64, 63), 256, 0, stream>>>(
      Hb, 256, Ws1, 10, idx1, cnt, S + 2 * NROWS);
  picked_kernel<<<1024, 256, 0, stream>>>(logits, targets, Wh, Ws0, Ws1, Hb, P);
  loss_kernel<<<1, 256, 0, stream>>>(targets, S, P, out);
}